// Round 4
// baseline (226.973 us; speedup 1.0000x reference)
//
#include <hip/hip_runtime.h>
#include <hip/hip_bf16.h>
#include <math.h>

// MoE Router V2: x(16384,2048) fp32, W(128,2048) fp32, bias(128) fp32
// out = [weights(16384,8) fp32 | indices(16384,8) as fp32]
//
// R4: same split-bf16 (3-plane, 6 MFMA) GEMM as R3 but:
//   - LDS plane-row stride padded 32->40 shorts (80 B = 5x16 B): staging
//     writes and frag reads both verified conflict-free (R3's 64 B stride
//     gave 16-way write / 8-way read conflicts -> ~75 us instead of ~23).
//   - register prefetch of next chunk's global loads, issued before the
//     MFMA barrier so the ~500 cyc latency hides behind compute.
// Kernel B: combine partials + softmax + stable top-8 + L2 normalize.

#define NE     128
#define TOKT   128   // tokens per tile
#define KC     32    // k per chunk (one 16x16x32 MFMA step)
#define KROW   40    // padded row stride in shorts (80 B, 16B-aligned, conflict-free)
#define KS     4     // split-K
#define DMODEL 2048
#define DSLICE (DMODEL / KS)  // 512

typedef __attribute__((ext_vector_type(8))) short short8;
typedef __attribute__((ext_vector_type(4))) float f32x4;

union S8 { short s[8]; short8 v; };

// split one fp32 into 3 truncated bf16 planes (exact residuals)
__device__ __forceinline__ void split3(float f, S8& hi, S8& mi, S8& lo, int j) {
  const unsigned u0 = __float_as_uint(f);
  const float hif = __uint_as_float(u0 & 0xFFFF0000u);
  const float r1 = f - hif;                      // exact
  const unsigned u1 = __float_as_uint(r1);
  const float mif = __uint_as_float(u1 & 0xFFFF0000u);
  const float r2 = r1 - mif;                     // exact
  hi.s[j] = (short)(u0 >> 16);
  mi.s[j] = (short)(u1 >> 16);
  lo.s[j] = (short)(__float_as_uint(r2) >> 16);
}

__device__ __forceinline__ void split8(const float4& a0, const float4& a1,
                                       S8& hi, S8& mi, S8& lo) {
  split3(a0.x, hi, mi, lo, 0); split3(a0.y, hi, mi, lo, 1);
  split3(a0.z, hi, mi, lo, 2); split3(a0.w, hi, mi, lo, 3);
  split3(a1.x, hi, mi, lo, 4); split3(a1.y, hi, mi, lo, 5);
  split3(a1.z, hi, mi, lo, 6); split3(a1.w, hi, mi, lo, 7);
}

__global__ __launch_bounds__(256) void logits_mfma(
    const float* __restrict__ x, const float* __restrict__ w,
    float* __restrict__ part, int N) {
  __shared__ short xs[3][TOKT * KROW];
  __shared__ short wsm[3][NE * KROW];

  const int tid  = threadIdx.x;
  const int wave = tid >> 6;
  const int lane = tid & 63;
  const int wm = wave >> 1;        // wave-grid 2x2: m half
  const int wn = wave & 1;         // n half
  const int quad = lane >> 4;
  const int l16  = lane & 15;
  const size_t tokBase = (size_t)blockIdx.x * TOKT;
  const int d0 = blockIdx.y * DSLICE;

  // staging assignment: 2 threads per row, 16 consecutive k each
  const int r = tid >> 1;          // row 0..127 (token row and expert row)
  const int h = tid & 1;           // k half (0 or 16)

  const float* gx = x + (tokBase + r) * DMODEL + d0 + h * 16;
  const float* gw = w + (size_t)r * DMODEL + d0 + h * 16;

  f32x4 acc[4][4];
#pragma unroll
  for (int i = 0; i < 4; ++i)
#pragma unroll
    for (int j = 0; j < 4; ++j) acc[i][j] = (f32x4)(0.f);

  // prefetch chunk 0: 4 float4 of x, 4 of w per thread
  float4 px0 = *(const float4*)(gx + 0);
  float4 px1 = *(const float4*)(gx + 4);
  float4 px2 = *(const float4*)(gx + 8);
  float4 px3 = *(const float4*)(gx + 12);
  float4 pw0 = *(const float4*)(gw + 0);
  float4 pw1 = *(const float4*)(gw + 4);
  float4 pw2 = *(const float4*)(gw + 8);
  float4 pw3 = *(const float4*)(gw + 12);

  for (int kc = 0; kc < DSLICE; kc += KC) {
    __syncthreads();   // previous chunk's frag reads done
    // ---- split prefetched regs into planes, store to LDS ----
    {
      S8 hi, mi, lo;
      const int kk0 = h * 16;
      split8(px0, px1, hi, mi, lo);
      *(short8*)&xs[0][r * KROW + kk0] = hi.v;
      *(short8*)&xs[1][r * KROW + kk0] = mi.v;
      *(short8*)&xs[2][r * KROW + kk0] = lo.v;
      split8(px2, px3, hi, mi, lo);
      *(short8*)&xs[0][r * KROW + kk0 + 8] = hi.v;
      *(short8*)&xs[1][r * KROW + kk0 + 8] = mi.v;
      *(short8*)&xs[2][r * KROW + kk0 + 8] = lo.v;
      split8(pw0, pw1, hi, mi, lo);
      *(short8*)&wsm[0][r * KROW + kk0] = hi.v;
      *(short8*)&wsm[1][r * KROW + kk0] = mi.v;
      *(short8*)&wsm[2][r * KROW + kk0] = lo.v;
      split8(pw2, pw3, hi, mi, lo);
      *(short8*)&wsm[0][r * KROW + kk0 + 8] = hi.v;
      *(short8*)&wsm[1][r * KROW + kk0 + 8] = mi.v;
      *(short8*)&wsm[2][r * KROW + kk0 + 8] = lo.v;
    }
    // ---- issue next chunk's global loads (latency hides behind MFMA) ----
    if (kc + KC < DSLICE) {
      const float* nx = gx + kc + KC;
      const float* nw = gw + kc + KC;
      px0 = *(const float4*)(nx + 0);
      px1 = *(const float4*)(nx + 4);
      px2 = *(const float4*)(nx + 8);
      px3 = *(const float4*)(nx + 12);
      pw0 = *(const float4*)(nw + 0);
      pw1 = *(const float4*)(nw + 4);
      pw2 = *(const float4*)(nw + 8);
      pw3 = *(const float4*)(nw + 12);
    }
    __syncthreads();   // LDS tiles ready

    // ---- fragments + 6-plane MFMAs ----
    short8 af[4][3];
#pragma unroll
    for (int mt = 0; mt < 4; ++mt)
#pragma unroll
      for (int p = 0; p < 3; ++p)
        af[mt][p] = *(const short8*)&xs[p][(wm * 64 + mt * 16 + l16) * KROW + quad * 8];

#pragma unroll
    for (int nt = 0; nt < 4; ++nt) {
      short8 bf[3];
#pragma unroll
      for (int p = 0; p < 3; ++p)
        bf[p] = *(const short8*)&wsm[p][(wn * 64 + nt * 16 + l16) * KROW + quad * 8];
#pragma unroll
      for (int mt = 0; mt < 4; ++mt) {
        f32x4 c = acc[mt][nt];
        c = __builtin_amdgcn_mfma_f32_16x16x32_bf16(af[mt][0], bf[0], c, 0, 0, 0); // x1w1
        c = __builtin_amdgcn_mfma_f32_16x16x32_bf16(af[mt][0], bf[1], c, 0, 0, 0); // x1w2
        c = __builtin_amdgcn_mfma_f32_16x16x32_bf16(af[mt][1], bf[0], c, 0, 0, 0); // x2w1
        c = __builtin_amdgcn_mfma_f32_16x16x32_bf16(af[mt][0], bf[2], c, 0, 0, 0); // x1w3
        c = __builtin_amdgcn_mfma_f32_16x16x32_bf16(af[mt][2], bf[0], c, 0, 0, 0); // x3w1
        c = __builtin_amdgcn_mfma_f32_16x16x32_bf16(af[mt][1], bf[1], c, 0, 0, 0); // x2w2
        acc[mt][nt] = c;
      }
    }
  }

  // ---- epilogue: partials[kb][tok][exp]; C/D: col=lane&15, row=quad*4+reg ----
#pragma unroll
  for (int mt = 0; mt < 4; ++mt)
#pragma unroll
    for (int nt = 0; nt < 4; ++nt) {
      const int ex = wn * 64 + nt * 16 + l16;
#pragma unroll
      for (int reg = 0; reg < 4; ++reg) {
        const size_t tok = tokBase + wm * 64 + mt * 16 + quad * 4 + reg;
        part[((size_t)blockIdx.y * N + tok) * NE + ex] = acc[mt][nt][reg];
      }
    }
}

// One wave (64 lanes) per token; lane owns experts {lane, lane+64}.
__global__ __launch_bounds__(256) void router_topk(
    const float* __restrict__ part, const float* __restrict__ bias,
    float* __restrict__ outW, float* __restrict__ outI, int ks, int N) {
  const int wave = threadIdx.x >> 6;
  const int lane = threadIdx.x & 63;
  const int token = blockIdx.x * 4 + wave;
  if (token >= N) return;

  float l0 = 0.f, l1 = 0.f;
  for (int k = 0; k < ks; ++k) {
    const float* p = part + ((size_t)k * N + token) * NE;
    l0 += p[lane];
    l1 += p[lane + 64];
  }

  float m = fmaxf(l0, l1);
#pragma unroll
  for (int off = 1; off < 64; off <<= 1) m = fmaxf(m, __shfl_xor(m, off));
  const float ev0 = __expf(l0 - m);
  const float ev1 = __expf(l1 - m);
  float zs = ev0 + ev1;
#pragma unroll
  for (int off = 1; off < 64; off <<= 1) zs += __shfl_xor(zs, off);
  const float s0 = ev0 / zs;
  const float s1 = ev1 / zs;

  float b0 = s0 + bias[lane];
  float b1 = s1 + bias[lane + 64];

  float myv = 0.f;
  int myi = 0;
  float ss = 0.f;
#pragma unroll
  for (int rnd = 0; rnd < 8; ++rnd) {
    float key; int idx;
    if (b0 >= b1) { key = b0; idx = lane; }
    else          { key = b1; idx = lane + 64; }
#pragma unroll
    for (int off = 1; off < 64; off <<= 1) {
      const float k2 = __shfl_xor(key, off);
      const int   i2 = __shfl_xor(idx, off);
      if (k2 > key || (k2 == key && i2 < idx)) { key = k2; idx = i2; }
    }
    const float cand = (idx < 64) ? s0 : s1;
    const float sw = __shfl(cand, idx & 63);
    ss = fmaf(sw, sw, ss);
    if (lane == rnd) { myv = sw; myi = idx; }
    if (lane == (idx & 63)) { if (idx < 64) b0 = -INFINITY; else b1 = -INFINITY; }
  }

  const float inv = 1.f / sqrtf(ss);
  if (lane < 8) {
    outW[(size_t)token * 8 + lane] = myv * inv;
    outI[(size_t)token * 8 + lane] = (float)myi;
  }
}

extern "C" void kernel_launch(void* const* d_in, const int* in_sizes, int n_in,
                              void* d_out, int out_size, void* d_ws, size_t ws_size,
                              hipStream_t stream) {
  const float* x    = (const float*)d_in[0];
  const float* w    = (const float*)d_in[1];
  const float* bias = (const float*)d_in[2];
  float* out = (float*)d_out;

  const int N = in_sizes[0] / DMODEL;  // 16384 tokens
  float* part = (float*)d_ws;          // KS * N * 128 * 4 B = 33.5 MB

  logits_mfma<<<dim3(N / TOKT, KS), 256, 0, stream>>>(x, w, part, N);
  router_topk<<<(N + 3) / 4, 256, 0, stream>>>(part, bias, out, out + (size_t)N * 8, KS, N);
}